// Round 1
// baseline (137.832 us; speedup 1.0000x reference)
//
#include <hip/hip_runtime.h>
#include <math.h>

#define NG 128
#define NIN 512
#define OFF1 4194304   // 8192*512
#define OFF2 8388608   // 2*8192*512
#define OFF3 9437184   // OFF2 + 8192*128

#define INV_SQRT_2PI 0.3989422804014327f
#define INV_SQRT2    0.7071067811865476f

typedef float f32x4 __attribute__((ext_vector_type(4)));

// fast tanh: 1 - 2/(e^{2x}+1). v_exp_f32 + v_rcp_f32, ~2ulp.
__device__ __forceinline__ float ftanh(float x){
    float e = __expf(2.0f*x);
    float r = __builtin_amdgcn_rcpf(e + 1.0f);
    return 1.0f - 2.0f*r;
}
__device__ __forceinline__ float frcp(float x){ return __builtin_amdgcn_rcpf(x); }

__device__ __forceinline__ float gelu_f(float x){
    return 0.5f*x*(1.0f + erff(x*INV_SQRT2));
}
__device__ __forceinline__ float gelu_df(float x){
    return 0.5f*(1.0f + erff(x*INV_SQRT2)) + x*INV_SQRT_2PI*__expf(-0.5f*x*x);
}

// Kernel A: fully fused. Forward computed ONCE per (g,row) pair.
//  - writes u_z, u, u_zz finals (NT stores)
//  - writes pde WITHOUT the dS_sum term (normal store -> L2 for k_fix)
//  - emits per-block dSdt partials (reuses the q[] vector: dSdt = q . dtv)
//  - k_pre's work (time-MLP tv/dtv + truncnorm consts) inlined as a
//    uniform per-thread prologue (~250 VALU ops, hidden under memory)
__global__ __launch_bounds__(256) void k_all(const float* __restrict__ z,
    const float* __restrict__ Wx, const float* __restrict__ bx,
    const float* __restrict__ Wf, const float* __restrict__ bf,
    const float* __restrict__ Wo, const float* __restrict__ bo,
    const float* __restrict__ betap,
    const float* __restrict__ ts, const float* __restrict__ mup,
    const float* __restrict__ sigp,
    const float* __restrict__ Wt, const float* __restrict__ bt,
    const float* __restrict__ Wt2, const float* __restrict__ bt2,
    float* __restrict__ partial, float* __restrict__ out){
    const int tid  = threadIdx.x;
    const int gidx = tid & 127;
    const int row0 = blockIdx.x*4 + (tid>>7)*2;   // rows row0, row0+1

    // ---- uniform prologue: truncnorm consts (was k_pre/consts) ----
    const float t     = ts[0];
    const float mu    = mup[0];
    const float sigma = sigp[0];
    const float sig2    = sigma*sigma + 1e-5f;
    const float dlp     = -1.0f/sig2;
    const float inv_s4  = 1.0f/(sigma*sigma*sigma*sigma + 1e-5f);
    const float phi_b   = 0.5f*(1.0f+erff((10.0f-mu)/sigma*INV_SQRT2));
    const float phi_a   = 0.5f*(1.0f+erff((-10.0f-mu)/sigma*INV_SQRT2));
    const float invZ    = 1.0f/(phi_b-phi_a);
    const float inv_sig = 1.0f/sigma;
    const float inv_sig2 = frcp(sig2);

    // ---- time-MLP branch for this group (was k_pre tv/dtv) ----
    float tvA[4], dtvA[4];
    {
        const float f1 = 0.01f;                 // freqs = [1, 0.01] exactly
        float s0, c0, s1, c1;
        __sincosf(t, &s0, &c0);
        __sincosf(t*f1, &s1, &c1);
        float temb[4]  = { s0, s1, c0, c1 };
        float dtemb[4] = { c0, f1*c1, -s0, -f1*s1 };
        float tg[4], dg[4];
        #pragma unroll
        for (int i=0;i<4;i++){
            float a = bt[gidx*4+i], d = 0.0f;
            #pragma unroll
            for (int j=0;j<4;j++){
                float w = Wt[gidx*16+i*4+j];
                a += w*temb[j]; d += w*dtemb[j];
            }
            tg[i] = gelu_f(a);
            dg[i] = gelu_df(a)*d;
        }
        #pragma unroll
        for (int j=0;j<4;j++){
            float a = bt2[gidx*4+j], d = 0.0f;
            #pragma unroll
            for (int i=0;i<4;i++){
                float w = Wt2[gidx*16+j*4+i];
                a += w*tg[i]; d += w*dg[i];
            }
            tvA[j]  = a;
            dtvA[j] = d;
        }
    }

    // ---- per-group weights ----
    float wx[16], wf[16];
    #pragma unroll
    for (int i=0;i<4;i++){
        float4 a4 = ((const float4*)(Wx + gidx*16))[i];
        wx[i*4+0]=a4.x; wx[i*4+1]=a4.y; wx[i*4+2]=a4.z; wx[i*4+3]=a4.w;
        float4 b4 = ((const float4*)(Wf + gidx*16))[i];
        wf[i*4+0]=b4.x; wf[i*4+1]=b4.y; wf[i*4+2]=b4.z; wf[i*4+3]=b4.w;
    }
    float4 t4;
    t4 = ((const float4*)bx)[gidx];    float bxA[4]={t4.x,t4.y,t4.z,t4.w};
    t4 = ((const float4*)bf)[gidx];    float bfA[4]={t4.x,t4.y,t4.z,t4.w};
    t4 = ((const float4*)Wo)[gidx];    float w3[4] ={t4.x,t4.y,t4.z,t4.w};
    const float bo0 = bo[gidx];
    const float bb  = betap[gidx];

    // ---- interleaved forward for 2 rows (ILP on tanh chains) ----
    float zz[2][4], x_[2][4], xp[2][4], h_[2][4], hp[2][4], S[2], sp[2], q[2][4];
    #pragma unroll
    for (int r=0;r<2;r++){
        float4 zv = *((const float4*)(z + (row0+r)*NIN + gidx*4));
        zz[r][0]=zv.x; zz[r][1]=zv.y; zz[r][2]=zv.z; zz[r][3]=zv.w;
    }
    float u1[2][4];
    #pragma unroll
    for (int r=0;r<2;r++){
        #pragma unroll
        for (int i=0;i<4;i++){
            float a = bxA[i] + wx[i*4]*zz[r][0]+wx[i*4+1]*zz[r][1]
                             + wx[i*4+2]*zz[r][2]+wx[i*4+3]*zz[r][3];
            x_[r][i] = ftanh(a);
        }
    }
    #pragma unroll
    for (int r=0;r<2;r++){
        #pragma unroll
        for (int i=0;i<4;i++){
            xp[r][i] = 1.0f - x_[r][i]*x_[r][i];
            u1[r][i] = x_[r][i] + tvA[i];
        }
    }
    float a3[2] = { bo0, bo0 };
    #pragma unroll
    for (int r=0;r<2;r++){
        #pragma unroll
        for (int i=0;i<4;i++){
            float a = bfA[i] + wf[i*4]*u1[r][0]+wf[i*4+1]*u1[r][1]
                             + wf[i*4+2]*u1[r][2]+wf[i*4+3]*u1[r][3];
            h_[r][i] = ftanh(a);
        }
    }
    #pragma unroll
    for (int r=0;r<2;r++){
        #pragma unroll
        for (int i=0;i<4;i++){
            hp[r][i] = 1.0f - h_[r][i]*h_[r][i];
            a3[r] += w3[i]*h_[r][i];
        }
    }
    #pragma unroll
    for (int r=0;r<2;r++){ S[r] = ftanh(a3[r]); sp[r] = 1.0f - S[r]*S[r]; }
    #pragma unroll
    for (int r=0;r<2;r++){
        q[r][0]=q[r][1]=q[r][2]=q[r][3]=0.0f;
        #pragma unroll
        for (int i=0;i<4;i++){
            float vi = sp[r]*w3[i]*hp[r][i];
            #pragma unroll
            for (int j=0;j<4;j++) q[r][j] += vi*wf[i*4+j];
        }
    }

    // dS/dt for both rows: 8 FMAs reusing q (this replaces ALL of k_dsdt)
    float accd = q[0][0]*dtvA[0]+q[0][1]*dtvA[1]+q[0][2]*dtvA[2]+q[0][3]*dtvA[3]
               + q[1][0]*dtvA[0]+q[1][1]*dtvA[1]+q[1][2]*dtvA[2]+q[1][3]*dtvA[3];

    // ---- epilogue per row ----
    #pragma unroll
    for (int r=0;r<2;r++){
        float Bm[16];
        #pragma unroll
        for (int i=0;i<4;i++){
            #pragma unroll
            for (int n=0;n<4;n++){
                float s = 0.0f;
                #pragma unroll
                for (int k=0;k<4;k++) s += wf[i*4+k]*xp[r][k]*wx[k*4+n];
                Bm[i*4+n]=s;
            }
        }
        float w3hp[4], v[4];
        #pragma unroll
        for (int i=0;i<4;i++){ w3hp[i]=w3[i]*hp[r][i]; v[i]=sp[r]*w3hp[i]; }
        float c[4];
        #pragma unroll
        for (int n=0;n<4;n++){
            float s=0.0f;
            #pragma unroll
            for (int i=0;i<4;i++) s += w3hp[i]*Bm[i*4+n];
            c[n]=s;
        }
        const float alpha = -2.0f*S[r]*sp[r];
        float bet[4], gam[4];
        #pragma unroll
        for (int i=0;i<4;i++){
            bet[i] = -2.0f*h_[r][i]*v[i];
            gam[i] = -2.0f*x_[r][i]*xp[r][i]*q[r][i];
        }

        float rho[4], nlp[4], dpp[4];
        #pragma unroll
        for (int j=0;j<4;j++){
            float zj = zz[r][j];
            float xs = zj > 10.0f ? zj+100.0f : zj;
            xs = xs < -10.0f ? xs-100.0f : xs;
            float xn = (xs-mu)*inv_sig;
            float dens = __expf(-0.5f*xn*xn)*INV_SQRT_2PI;
            dens = (xn > 10.0f || xn < -10.0f) ? 0.0f : dens;
            rho[j] = dens*invZ + 1e-10f;
            nlp[j] = -(zj-mu)*inv_sig2;
            float d = zj-mu;
            dpp[j] = (d*d - sigma*sigma)*inv_s4;
        }
        float u_val = S[r] - bb*__logf(rho[0]*rho[1]*rho[2]*rho[3]);

        float rc=0.0f, scs=0.0f;
        #pragma unroll
        for (int j=0;j<4;j++){ rc += rho[j]*c[j]; scs += c[j]; }
        float rB[4], sB[4], rA[4], sA[4];
        #pragma unroll
        for (int i=0;i<4;i++){
            float r1=0.0f, s=0.0f, r2=0.0f, s2=0.0f;
            #pragma unroll
            for (int j=0;j<4;j++){
                r1 += rho[j]*Bm[i*4+j]; s  += Bm[i*4+j];
                r2 += rho[j]*wx[i*4+j]; s2 += wx[i*4+j];
            }
            rB[i]=r1; sB[i]=s; rA[i]=r2; sA[i]=s2;
        }

        float pde[4], uz[4], uzz[4];
        #pragma unroll
        for (int k=0;k<4;k++){
            float corr = alpha*rc*c[k];
            float hsum = alpha*scs*c[k];
            #pragma unroll
            for (int i=0;i<4;i++){
                corr += bet[i]*rB[i]*Bm[i*4+k];
                hsum += bet[i]*sB[i]*Bm[i*4+k];
                corr += gam[i]*rA[i]*wx[i*4+k];
                hsum += gam[i]*sA[i]*wx[i*4+k];
            }
            float uzk = sp[r]*c[k] - bb*nlp[k];
            uz[k]  = uzk;
            uzz[k] = hsum - bb*dlp;
            // NOTE: dS_sum deliberately omitted — k_fix adds it in place.
            pde[k] = bb*corr*frcp(rho[k]+1e-5f)
                   + 0.5f*uzk*uzk + 0.125f*bb*bb*(nlp[k]*nlp[k] - 2.0f*dpp[k]);
        }

        const int base = (row0+r)*NIN + gidx*4;
        f32x4 pdev = { pde[0], pde[1], pde[2], pde[3] };
        f32x4 uzv  = { uz[0],  uz[1],  uz[2],  uz[3]  };
        f32x4 uzzv = { uzz[0], uzz[1], uzz[2], uzz[3] };
        *((f32x4*)(out + base)) = pdev;   // normal store: stay in L2 for k_fix
        __builtin_nontemporal_store(uzv,  (f32x4*)(out + OFF1 + base));
        __builtin_nontemporal_store(u_val, out + OFF2 + (row0+r)*NG + gidx);
        __builtin_nontemporal_store(uzzv, (f32x4*)(out + OFF3 + base));
    }

    // ---- per-block dSdt partial (deterministic, no atomics) ----
    __shared__ float sred[256];
    sred[tid] = accd;
    __syncthreads();
    if (tid < 128) partial[blockIdx.x*128 + tid] = sred[tid] + sred[tid+128];
}

// Kernel B: reduce 2048 partials per group -> dsum[g]. 128 blocks x 256.
__global__ __launch_bounds__(256) void k_red(const float* __restrict__ partial,
                                             float* __restrict__ dsum){
    int g = blockIdx.x;
    int tid = threadIdx.x;
    float a = 0.0f;
    for (int i=tid;i<2048;i+=256) a += partial[i*128+g];
    __shared__ float s[256];
    s[tid] = a;
    __syncthreads();
    if (tid < 64){
        a = s[tid] + s[tid+64] + s[tid+128] + s[tid+192];
        #pragma unroll
        for (int o=32;o>0;o>>=1) a += __shfl_down(a, o);
        if (tid==0) dsum[g] = a;
    }
}

// Kernel C: pde += dsum[g], in place. Pure BW pass (33.6 MB RMW ~ 5.5 us).
// float4 idx within a row == g, so each float4 needs exactly one dsum value;
// idx and idx+524288 share g (524288 % 128 == 0).
__global__ __launch_bounds__(256) void k_fix(const float* __restrict__ dsum,
                                             float* __restrict__ out){
    const int idx = blockIdx.x*256 + threadIdx.x;     // [0, 524288)
    const float ds = dsum[idx & 127];
    f32x4* p = (f32x4*)out;
    f32x4 v = p[idx];
    v.x += ds; v.y += ds; v.z += ds; v.w += ds;
    p[idx] = v;
    const int idx2 = idx + 524288;
    f32x4 w = p[idx2];
    w.x += ds; w.y += ds; w.z += ds; w.w += ds;
    p[idx2] = w;
}

extern "C" void kernel_launch(void* const* d_in, const int* in_sizes, int n_in,
                              void* d_out, int out_size, void* d_ws, size_t ws_size,
                              hipStream_t stream){
    (void)in_sizes; (void)n_in; (void)out_size; (void)ws_size;
    const float* z     = (const float*)d_in[0];
    const float* ts    = (const float*)d_in[1];
    const float* mu    = (const float*)d_in[2];
    const float* sigma = (const float*)d_in[3];
    const float* Wx    = (const float*)d_in[4];
    const float* bx    = (const float*)d_in[5];
    const float* Wt    = (const float*)d_in[6];
    const float* bt    = (const float*)d_in[7];
    const float* Wt2   = (const float*)d_in[8];
    const float* bt2   = (const float*)d_in[9];
    const float* Wf    = (const float*)d_in[10];
    const float* bf    = (const float*)d_in[11];
    const float* Wo    = (const float*)d_in[12];
    const float* bo    = (const float*)d_in[13];
    const float* beta  = (const float*)d_in[14];
    float* out = (float*)d_out;

    float* ws      = (float*)d_ws;
    float* dsum    = ws;            // 128
    float* partial = ws + 128;      // 2048*128 = 262144

    k_all<<<2048,256, 0, stream>>>(z, Wx, bx, Wf, bf, Wo, bo, beta,
                                   ts, mu, sigma, Wt, bt, Wt2, bt2,
                                   partial, out);
    k_red<<<128, 256, 0, stream>>>(partial, dsum);
    k_fix<<<2048,256, 0, stream>>>(dsum, out);
}